// Round 7
// baseline (374.749 us; speedup 1.0000x reference)
//
#include <hip/hip_runtime.h>
#include <hip/hip_bf16.h>
#include <math.h>

#define N_NODES 4096
#define F_INN   256
#define F_OUTT  64
#define HID     64
#define MAXDEG  64

typedef __attribute__((ext_vector_type(8))) short bf16x8;
typedef __attribute__((ext_vector_type(4))) float f32x4;

// Scratch in device globals (no ws_size dependence). Fully rewritten each call.
__device__ int    g_mode;                    // 0 = fp32 inputs, 1 = bf16 inputs
__device__ int    g_anyArr[64];              // per-block detector flags
__device__ float  g_Wh [N_NODES * F_OUTT];
__device__ float  g_s1 [N_NODES];
__device__ float  g_s2 [N_NODES];
__device__ int    g_rev[N_NODES * MAXDEG];
__device__ int    g_perm[N_NODES];
__device__ float4 g_GX [N_NODES * F_OUTT];   // fp32 path only
__device__ __align__(16) unsigned short g_xhi[N_NODES * F_OUTT]; // bf16 hi of Wh2
__device__ __align__(16) unsigned short g_xlo[N_NODES * F_OUTT]; // bf16 lo of Wh2

__device__ __forceinline__ float bf2f(unsigned short u) {
  union { unsigned int i; float f; } v; v.i = ((unsigned int)u) << 16; return v.f;
}
__device__ __forceinline__ unsigned short f2bf(float f) {
  union { __hip_bfloat16 b; unsigned short u; } v; v.b = __float2bfloat16(f); return v.u;
}

__device__ __forceinline__ float bcastf(float v, int l) {
  return __int_as_float(__builtin_amdgcn_readlane(__float_as_int(v), l));
}

__device__ __forceinline__ float sigm(float x) { return 1.f / (1.f + __expf(-x)); }
__device__ __forceinline__ float tanh_fast(float x) { return 1.f - 2.f / (1.f + __expf(2.f * x)); }

__device__ __forceinline__ bf16x8 zfrag() {
  bf16x8 z;
  #pragma unroll
  for (int i = 0; i < 8; i++) z[i] = 0;
  return z;
}

// split float8 (as two float4) into exact-ish bf16 hi/lo fragments
__device__ __forceinline__ void hilo(float4 a, float4 b, bf16x8& hi, bf16x8& lo) {
  float v[8] = {a.x, a.y, a.z, a.w, b.x, b.y, b.z, b.w};
  #pragma unroll
  for (int i = 0; i < 8; i++) {
    unsigned short h = f2bf(v[i]);
    hi[i] = (short)h;
    lo[i] = (short)f2bf(v[i] - bf2f(h));
  }
}

#define MFMA16(a, b, c) __builtin_amdgcn_mfma_f32_16x16x32_bf16((a), (b), (c), 0, 0, 0)

// D0: parallel dtype detector (fp32 adj words have zero low16; bf16 doesn't).
__global__ __launch_bounds__(256) void k_detect(const unsigned int* __restrict__ aw) {
  __shared__ int any;
  if (threadIdx.x == 0) any = 0;
  __syncthreads();
  const uint4 v = ((const uint4*)aw)[blockIdx.x * 256 + threadIdx.x];
  int loc = (int)((v.x & 0xFFFFu) | (v.y & 0xFFFFu) | (v.z & 0xFFFFu) | (v.w & 0xFFFFu));
  if (loc) atomicOr(&any, 1);
  __syncthreads();
  if (threadIdx.x == 0) g_anyArr[blockIdx.x] = any;
}

// S1: reduce detector flags -> g_mode; counting sort by seq_length descending.
__global__ __launch_bounds__(256) void k_sort(const int* __restrict__ seq) {
  __shared__ int hist[MAXDEG + 1];
  __shared__ int offs[MAXDEG + 1];
  const int tid = threadIdx.x;
  if (tid <= MAXDEG) hist[tid] = 0;
  __syncthreads();
  if (tid == 0) {
    int any = 0;
    for (int b = 0; b < 64; b++) any |= g_anyArr[b];
    g_mode = any ? 1 : 0;
  }
  for (int i = tid; i < N_NODES; i += 256)
    atomicAdd(&hist[min(max(seq[i], 0), MAXDEG)], 1);
  __syncthreads();
  if (tid == 0) {
    int run = 0;
    for (int L = MAXDEG; L >= 0; L--) { offs[L] = run; run += hist[L]; }
  }
  __syncthreads();
  for (int i = tid; i < N_NODES; i += 256) {
    int p = atomicAdd(&offs[min(max(seq[i], 0), MAXDEG)], 1);
    g_perm[p] = i;
  }
}

// K1: Wh = h @ W (fp64 acc), s1/s2 fp64 dots. Unchanged from r6.
__global__ __launch_bounds__(256) void k_wh(
    const void* __restrict__ h, const void* __restrict__ W, const void* __restrict__ a)
{
  const bool bf16 = (g_mode == 1);
  __shared__ float Ws[F_INN * F_OUTT];   // 64 KB
  const int tid = threadIdx.x;
  if (bf16) {
    const ushort4* Wu = (const ushort4*)W;
    for (int v = tid; v < F_INN * F_OUTT / 4; v += 256) {
      ushort4 u = Wu[v];
      ((float4*)Ws)[v] = make_float4(bf2f(u.x), bf2f(u.y), bf2f(u.z), bf2f(u.w));
    }
  } else {
    const float4* Wf = (const float4*)W;
    for (int v = tid; v < F_INN * F_OUTT / 4; v += 256) ((float4*)Ws)[v] = Wf[v];
  }
  __syncthreads();
  const int wave = tid >> 6, lane = tid & 63;
  const int row = blockIdx.x * 4 + wave;
  float hr0, hr1, hr2, hr3;
  if (bf16) {
    ushort4 v = ((const ushort4*)((const unsigned short*)h + row * F_INN))[lane];
    hr0 = bf2f(v.x); hr1 = bf2f(v.y); hr2 = bf2f(v.z); hr3 = bf2f(v.w);
  } else {
    float4 v = ((const float4*)((const float*)h + row * F_INN))[lane];
    hr0 = v.x; hr1 = v.y; hr2 = v.z; hr3 = v.w;
  }
  double acc = 0.0;
  #pragma unroll 8
  for (int l = 0; l < 64; l++) {
    float h0 = bcastf(hr0, l), h1 = bcastf(hr1, l);
    float h2 = bcastf(hr2, l), h3 = bcastf(hr3, l);
    acc += (double)h0 * (double)Ws[(l * 4 + 0) * F_OUTT + lane];
    acc += (double)h1 * (double)Ws[(l * 4 + 1) * F_OUTT + lane];
    acc += (double)h2 * (double)Ws[(l * 4 + 2) * F_OUTT + lane];
    acc += (double)h3 * (double)Ws[(l * 4 + 3) * F_OUTT + lane];
  }
  const float whv = (float)acc;
  g_Wh[row * F_OUTT + lane] = whv;
  float a1, a2;
  if (bf16) {
    a1 = bf2f(((const unsigned short*)a)[lane]);
    a2 = bf2f(((const unsigned short*)a)[F_OUTT + lane]);
  } else {
    a1 = ((const float*)a)[lane];
    a2 = ((const float*)a)[F_OUTT + lane];
  }
  double t1 = (double)whv * (double)a1;
  double t2 = (double)whv * (double)a2;
  #pragma unroll
  for (int off = 32; off > 0; off >>= 1) {
    t1 += __shfl_down(t1, off);
    t2 += __shfl_down(t2, off);
  }
  if (lane == 0) { g_s1[row] = (float)t1; g_s2[row] = (float)t2; }
}

// K2: attention. Same math as r6; bf16 mode stores Wh2 as bf16 hi/lo (for the
// MFMA LSTM); fp32 mode keeps the fused-GX path.
__global__ __launch_bounds__(256) void k_att(
    const void* __restrict__ adj, const void* __restrict__ w_ih)
{
  const bool bf16 = (g_mode == 1);
  const int i = blockIdx.x, tid = threadIdx.x;
  __shared__ int    nbr[MAXDEG];
  __shared__ float  att_s[MAXDEG];
  __shared__ int    sorted_j[MAXDEG];
  __shared__ double part[4][F_OUTT];
  __shared__ float  wh2row[F_OUTT];
  __shared__ int    cnt;
  if (tid == 0) cnt = 0;
  __syncthreads();
  if (bf16) {
    const uint4* ar = (const uint4*)((const unsigned short*)adj + (size_t)i * N_NODES);
    for (int c = tid; c < N_NODES / 8; c += 256) {
      uint4 v = ar[c];
      unsigned int w[4] = {v.x, v.y, v.z, v.w};
      #pragma unroll
      for (int k = 0; k < 4; k++) {
        if (w[k] & 0x0000FFFFu) { int p = atomicAdd(&cnt, 1); if (p < MAXDEG) nbr[p] = c*8 + k*2; }
        if (w[k] & 0xFFFF0000u) { int p = atomicAdd(&cnt, 1); if (p < MAXDEG) nbr[p] = c*8 + k*2 + 1; }
      }
    }
  } else {
    const float4* ar = (const float4*)((const float*)adj + (size_t)i * N_NODES);
    for (int c = tid; c < N_NODES / 4; c += 256) {
      float4 v = ar[c];
      if (v.x != 0.0f) { int p = atomicAdd(&cnt, 1); if (p < MAXDEG) nbr[p] = c*4;     }
      if (v.y != 0.0f) { int p = atomicAdd(&cnt, 1); if (p < MAXDEG) nbr[p] = c*4 + 1; }
      if (v.z != 0.0f) { int p = atomicAdd(&cnt, 1); if (p < MAXDEG) nbr[p] = c*4 + 2; }
      if (v.w != 0.0f) { int p = atomicAdd(&cnt, 1); if (p < MAXDEG) nbr[p] = c*4 + 3; }
    }
  }
  __syncthreads();
  const int L = min(cnt, MAXDEG);
  float ef = -3.0e38f; int jn = 0x7fffffff;
  if (tid < L) {
    jn = nbr[tid];
    float s = g_s1[i] + g_s2[jn];
    ef = (s > 0.0f) ? s : 0.2f * s;
  }
  float af = 0.0f;
  if (tid < 64) {
    float m = ef;
    #pragma unroll
    for (int off = 32; off > 0; off >>= 1) m = fmaxf(m, __shfl_down(m, off));
    m = __shfl(m, 0);
    double p = (tid < L) ? exp((double)(ef - m)) : 0.0;
    double ssum = p;
    #pragma unroll
    for (int off = 32; off > 0; off >>= 1) ssum += __shfl_down(ssum, off);
    ssum = __shfl(ssum, 0);
    af = (float)(p / ssum);
    att_s[tid] = af;
  }
  __syncthreads();
  if (tid < L) {
    int rank = 0;
    for (int q = 0; q < L; q++) {
      float aq = att_s[q]; int jq = nbr[q];
      if (aq > af || (aq == af && jq < jn)) rank++;
    }
    sorted_j[rank] = jn;
  }
  {
    const int wave = tid >> 6, lane = tid & 63;
    double acc = 0.0;
    for (int q = wave; q < L; q += 4)
      acc += (double)att_s[q] * (double)g_Wh[(size_t)nbr[q] * F_OUTT + lane];
    part[wave][lane] = acc;
  }
  __syncthreads();
  if (tid < MAXDEG)
    g_rev[i * MAXDEG + tid] = (tid < L) ? sorted_j[L - 1 - tid] : 0;
  if (tid < 64) {
    float x = (float)(part[0][tid] + part[1][tid] + part[2][tid] + part[3][tid]);
    wh2row[tid] = x;
    if (bf16) {
      unsigned short hi = f2bf(x);
      g_xhi[i * F_OUTT + tid] = hi;
      g_xlo[i * F_OUTT + tid] = f2bf(x - bf2f(hi));
    }
  }
  __syncthreads();
  if (!bf16) {   // fp32 fallback path needs GX
    double acc = 0.0;
    const float4* wrow = (const float4*)((const float*)w_ih + (size_t)tid * F_OUTT);
    #pragma unroll
    for (int q = 0; q < 16; q++) {
      float4 v = wrow[q];
      acc += (double)v.x * (double)wh2row[q*4 + 0];
      acc += (double)v.y * (double)wh2row[q*4 + 1];
      acc += (double)v.z * (double)wh2row[q*4 + 2];
      acc += (double)v.w * (double)wh2row[q*4 + 3];
    }
    ((float*)g_GX)[(i * F_OUTT + (tid & 63)) * 4 + (tid >> 6)] = (float)acc;
  }
}

// K4-MFMA (bf16 mode): 16 sorted rows per block; gates(16x256) =
// [h_hi|h_lo|x_hi|x_lo](16x256 bf16) @ [w_hh;w_hh;w_ih;w_ih]^T via
// v_mfma_f32_16x16x32_bf16. N split across 4 waves by tile stripe
// {w, w+4, w+8, w+12} so each wave owns full gate quads for units 16w..16w+15.
// hi/lo bf16 splitting keeps fp32-grade accuracy (bf16 products are exact in
// the fp32 MFMA accumulator). B fragments live in registers (loaded once).
// A layout: A[m=lane&15][k=quad*8+j]; B: [k=quad*8+j][n=lane&15];
// C: col=lane&15, row=quad*4+reg  (m89/m120-verified mappings).
__global__ __launch_bounds__(256, 1) void k_lstm_mfma(
    const void* __restrict__ w_hh, const void* __restrict__ w_ih,
    const void* __restrict__ b_ih, const void* __restrict__ b_hh,
    const int* __restrict__ seq, void* __restrict__ out)
{
  if (g_mode != 1) return;
  __shared__ __align__(16) float lds_h[2][16 * 68];   // +4 pad: 16B-aligned rows, bank-spread
  const int tid = threadIdx.x;
  const int w = tid >> 6, lane = tid & 63;
  const int q = lane >> 4, c = lane & 15;

  const int rb = blockIdx.x * 16;
  const int row_m = g_perm[rb + c] & (N_NODES - 1);       // A-row role (m == c)
  const int Ls_m  = min(max(seq[row_m], 0), MAXDEG);
  const int Lmax  = __builtin_amdgcn_readfirstlane(Ls_m); // rows sorted desc -> lane0 max
  int row_e[4], Ls_e[4];
  #pragma unroll
  for (int r = 0; r < 4; r++) {
    row_e[r] = g_perm[rb + q * 4 + r] & (N_NODES - 1);    // C-layout row q*4+r
    Ls_e[r]  = min(max(seq[row_e[r]], 0), MAXDEG);
  }

  // B fragments: gate g -> tile n = w + 4g -> col = 64g + 16w + c
  const unsigned short* whh = (const unsigned short*)w_hh;
  const unsigned short* wih = (const unsigned short*)w_ih;
  bf16x8 Bhh[4][2], Bih[4][2];
  #pragma unroll
  for (int g = 0; g < 4; g++) {
    const int col = 64 * g + 16 * w + c;
    #pragma unroll
    for (int ch = 0; ch < 2; ch++) {
      Bhh[g][ch] = *(const bf16x8*)(whh + col * 64 + ch * 32 + q * 8);
      Bih[g][ch] = *(const bf16x8*)(wih + col * 64 + ch * 32 + q * 8);
    }
  }
  float bs[4];
  #pragma unroll
  for (int g = 0; g < 4; g++) {
    const int col = 64 * g + 16 * w + c;
    bs[g] = bf2f(((const unsigned short*)b_ih)[col]) + bf2f(((const unsigned short*)b_hh)[col]);
  }

  const int rvb = row_m * MAXDEG;
  // preamble: x frags for t=0; src for t=1
  int src0 = g_rev[rvb] & (N_NODES - 1);
  bf16x8 xh0 = *(const bf16x8*)(g_xhi + src0 * F_OUTT + q * 8);
  bf16x8 xh1 = *(const bf16x8*)(g_xhi + src0 * F_OUTT + 32 + q * 8);
  bf16x8 xl0 = *(const bf16x8*)(g_xlo + src0 * F_OUTT + q * 8);
  bf16x8 xl1 = *(const bf16x8*)(g_xlo + src0 * F_OUTT + 32 + q * 8);
  int src_n = g_rev[rvb + 1] & (N_NODES - 1);

  bf16x8 hh0 = zfrag(), hh1 = zfrag(), hl0 = zfrag(), hl1 = zfrag();
  float cst[4] = {0.f, 0.f, 0.f, 0.f}, hst[4] = {0.f, 0.f, 0.f, 0.f};

  for (int t = 0; t < Lmax; t++) {
    // prefetch: src for t+2, x frags for t+1 (src_n preloaded -> no chain)
    const int src_n2 = g_rev[rvb + min(t + 2, MAXDEG - 1)] & (N_NODES - 1);
    const bf16x8 nxh0 = *(const bf16x8*)(g_xhi + src_n * F_OUTT + q * 8);
    const bf16x8 nxh1 = *(const bf16x8*)(g_xhi + src_n * F_OUTT + 32 + q * 8);
    const bf16x8 nxl0 = *(const bf16x8*)(g_xlo + src_n * F_OUTT + q * 8);
    const bf16x8 nxl1 = *(const bf16x8*)(g_xlo + src_n * F_OUTT + 32 + q * 8);

    f32x4 acc[4];
    #pragma unroll
    for (int g = 0; g < 4; g++) {
      f32x4 a; a[0] = bs[g]; a[1] = bs[g]; a[2] = bs[g]; a[3] = bs[g];
      a = MFMA16(hh0, Bhh[g][0], a);
      a = MFMA16(hh1, Bhh[g][1], a);
      a = MFMA16(hl0, Bhh[g][0], a);
      a = MFMA16(hl1, Bhh[g][1], a);
      a = MFMA16(xh0, Bih[g][0], a);
      a = MFMA16(xh1, Bih[g][1], a);
      a = MFMA16(xl0, Bih[g][0], a);
      a = MFMA16(xl1, Bih[g][1], a);
      acc[g] = a;
    }

    float* lh = lds_h[t & 1];
    #pragma unroll
    for (int r = 0; r < 4; r++) {
      float ig = sigm(acc[0][r]);
      float fg = sigm(acc[1][r]);
      float gg = tanh_fast(acc[2][r]);
      float og = sigm(acc[3][r]);
      float cn = fg * cst[r] + ig * gg;
      float hn = og * tanh_fast(cn);
      bool live = (t < Ls_e[r]);
      cst[r] = live ? cn : cst[r];
      hst[r] = live ? hn : hst[r];
      lh[(q * 4 + r) * 68 + 16 * w + c] = hst[r];
    }
    __syncthreads();
    // rebuild h A-fragments (row m = c): chunk0 units 8q..8q+7, chunk1 +32
    float4 v0 = *(const float4*)&lh[c * 68 + 8 * q];
    float4 v1 = *(const float4*)&lh[c * 68 + 8 * q + 4];
    float4 v2 = *(const float4*)&lh[c * 68 + 32 + 8 * q];
    float4 v3 = *(const float4*)&lh[c * 68 + 32 + 8 * q + 4];
    hilo(v0, v1, hh0, hl0);
    hilo(v2, v3, hh1, hl1);
    xh0 = nxh0; xh1 = nxh1; xl0 = nxl0; xl1 = nxl1;
    src_n = src_n2;
  }
  #pragma unroll
  for (int r = 0; r < 4; r++)
    ((__hip_bfloat16*)out)[row_e[r] * HID + 16 * w + c] = __float2bfloat16(hst[r]);
}

// K4 fp32 fallback (r6 kernel, proven): only runs if g_mode == 0.
__global__ __launch_bounds__(512, 2) void k_lstm_f32(
    const void* __restrict__ w_hh, const void* __restrict__ b_ih,
    const void* __restrict__ b_hh, const int* __restrict__ seq,
    void* __restrict__ out)
{
  if (g_mode != 0) return;
  __shared__ float4 whq[64 * 64];
  float* wf = (float*)whq;
  const int tid = threadIdx.x;
  for (int u = tid; u < 4096; u += 512) {
    const int row = u >> 4;
    const int j4  = (u & 15) * 4;
    const int g = row >> 6, d = row & 63;
    float4 v = ((const float4*)w_hh)[u];
    wf[((j4 + 0) * 64 + d) * 4 + g] = v.x;
    wf[((j4 + 1) * 64 + d) * 4 + g] = v.y;
    wf[((j4 + 2) * 64 + d) * 4 + g] = v.z;
    wf[((j4 + 3) * 64 + d) * 4 + g] = v.w;
  }
  __syncthreads();
  const int wave = tid >> 6, lane = tid & 63;
  const int base = (blockIdx.x * 8 + wave) * 2;
  int rows[2], Ls[2], rbase[2];
  #pragma unroll
  for (int r = 0; r < 2; r++) {
    rows[r]  = g_perm[base + r] & (N_NODES - 1);
    Ls[r]    = min(max(seq[rows[r]], 0), MAXDEG);
    rbase[r] = rows[r] * MAXDEG;
  }
  const int Lmax = max(Ls[0], Ls[1]);
  float bsum[4];
  #pragma unroll
  for (int g = 0; g < 4; g++)
    bsum[g] = ((const float*)b_ih)[g * 64 + lane] + ((const float*)b_hh)[g * 64 + lane];

  float hcur[2] = {0.f, 0.f}, ccur[2] = {0.f, 0.f};
  float4 gx[2];
  #pragma unroll
  for (int r = 0; r < 2; r++) {
    int src0 = g_rev[rbase[r]] & (N_NODES - 1);
    gx[r] = g_GX[src0 * F_OUTT + lane];
  }
  for (int t = 0; t < Lmax; t++) {
    float4 gxn[2];
    {
      const int tn = (t + 1) & (MAXDEG - 1);
      #pragma unroll
      for (int r = 0; r < 2; r++) {
        int srcn = g_rev[rbase[r] + tn] & (N_NODES - 1);
        gxn[r] = g_GX[srcn * F_OUTT + lane];
      }
    }
    float acc[2][4];
    #pragma unroll
    for (int r = 0; r < 2; r++) {
      acc[r][0] = bsum[0] + gx[r].x; acc[r][1] = bsum[1] + gx[r].y;
      acc[r][2] = bsum[2] + gx[r].z; acc[r][3] = bsum[3] + gx[r].w;
    }
    #pragma unroll 16
    for (int j = 0; j < 64; j++) {
      float4 wv = whq[j * 64 + lane];
      #pragma unroll
      for (int r = 0; r < 2; r++) {
        float hv = bcastf(hcur[r], j);
        acc[r][0] = fmaf(wv.x, hv, acc[r][0]);
        acc[r][1] = fmaf(wv.y, hv, acc[r][1]);
        acc[r][2] = fmaf(wv.z, hv, acc[r][2]);
        acc[r][3] = fmaf(wv.w, hv, acc[r][3]);
      }
    }
    #pragma unroll
    for (int r = 0; r < 2; r++) {
      float ig = sigm(acc[r][0]);
      float fg = sigm(acc[r][1]);
      float gg = tanh_fast(acc[r][2]);
      float og = sigm(acc[r][3]);
      float cn = fg * ccur[r] + ig * gg;
      float hn = og * tanh_fast(cn);
      bool live = (t < Ls[r]);
      ccur[r] = live ? cn : ccur[r];
      hcur[r] = live ? hn : hcur[r];
      gx[r] = gxn[r];
    }
  }
  #pragma unroll
  for (int r = 0; r < 2; r++)
    ((float*)out)[rows[r] * HID + lane] = hcur[r];
}

extern "C" void kernel_launch(void* const* d_in, const int* in_sizes, int n_in,
                              void* d_out, int out_size, void* d_ws, size_t ws_size,
                              hipStream_t stream) {
  (void)in_sizes; (void)n_in; (void)out_size; (void)d_ws; (void)ws_size;
  const void* h    = d_in[0];
  const void* adj  = d_in[1];
  const int*  seq  = (const int*)d_in[2];
  const void* W    = d_in[3];
  const void* a    = d_in[4];
  const void* w_ih = d_in[5];
  const void* w_hh = d_in[6];
  const void* b_ih = d_in[7];
  const void* b_hh = d_in[8];

  k_detect   <<<64,           256, 0, stream>>>((const unsigned int*)adj);
  k_sort     <<<1,            256, 0, stream>>>(seq);
  k_wh       <<<N_NODES / 4,  256, 0, stream>>>(h, W, a);
  k_att      <<<N_NODES,      256, 0, stream>>>(adj, w_ih);
  k_lstm_mfma<<<N_NODES / 16, 256, 0, stream>>>(w_hh, w_ih, b_ih, b_hh, seq, d_out);
  k_lstm_f32 <<<N_NODES / 16, 512, 0, stream>>>(w_hh, b_ih, b_hh, seq, d_out);
}

// Round 8
// 265.179 us; speedup vs baseline: 1.4132x; 1.4132x over previous
//
#include <hip/hip_runtime.h>
#include <hip/hip_bf16.h>
#include <math.h>

#define N_NODES 4096
#define F_INN   256
#define F_OUTT  64
#define HID     64
#define MAXDEG  64

typedef __attribute__((ext_vector_type(8))) short bf16x8;
typedef __attribute__((ext_vector_type(4))) float f32x4;

// Scratch in device globals (no ws_size dependence). Fully rewritten each call.
__device__ int    g_mode;                    // 0 = fp32 inputs, 1 = bf16 inputs
__device__ int    g_anyArr[64];              // per-block detector flags
__device__ float  g_Wh [N_NODES * F_OUTT];
__device__ float  g_s1 [N_NODES];
__device__ float  g_s2 [N_NODES];
__device__ int    g_rev[N_NODES * MAXDEG];
__device__ int    g_perm[N_NODES];
__device__ float4 g_GX [N_NODES * F_OUTT];   // per (node, unit): quad {i,f,g,o}

__device__ __forceinline__ float bf2f(unsigned short u) {
  union { unsigned int i; float f; } v; v.i = ((unsigned int)u) << 16; return v.f;
}
__device__ __forceinline__ unsigned short f2bf(float f) {
  union { __hip_bfloat16 b; unsigned short u; } v; v.b = __float2bfloat16(f); return v.u;
}

__device__ __forceinline__ float bcastf(float v, int l) {
  return __int_as_float(__builtin_amdgcn_readlane(__float_as_int(v), l));
}

__device__ __forceinline__ float sigm(float x) { return 1.f / (1.f + __expf(-x)); }
__device__ __forceinline__ float tanh_fast(float x) { return 1.f - 2.f / (1.f + __expf(2.f * x)); }

__device__ __forceinline__ bf16x8 zfrag() {
  bf16x8 z;
  #pragma unroll
  for (int i = 0; i < 8; i++) z[i] = 0;
  return z;
}

// split 8 fp32 (two float4) into bf16 hi/lo fragments (hi+lo ~ 17-bit mantissa)
__device__ __forceinline__ void hilo(float4 a, float4 b, bf16x8& hi, bf16x8& lo) {
  float v[8] = {a.x, a.y, a.z, a.w, b.x, b.y, b.z, b.w};
  #pragma unroll
  for (int i = 0; i < 8; i++) {
    unsigned short h = f2bf(v[i]);
    hi[i] = (short)h;
    lo[i] = (short)f2bf(v[i] - bf2f(h));
  }
}

#define MFMA16(a, b, c) __builtin_amdgcn_mfma_f32_16x16x32_bf16((a), (b), (c), 0, 0, 0)

// D0: parallel dtype detector (fp32 adj words have zero low16; bf16 doesn't).
__global__ __launch_bounds__(256) void k_detect(const unsigned int* __restrict__ aw) {
  __shared__ int any;
  if (threadIdx.x == 0) any = 0;
  __syncthreads();
  const uint4 v = ((const uint4*)aw)[blockIdx.x * 256 + threadIdx.x];
  int loc = (int)((v.x & 0xFFFFu) | (v.y & 0xFFFFu) | (v.z & 0xFFFFu) | (v.w & 0xFFFFu));
  if (loc) atomicOr(&any, 1);
  __syncthreads();
  if (threadIdx.x == 0) g_anyArr[blockIdx.x] = any;
}

// S1: reduce detector flags -> g_mode; counting sort by seq_length descending.
__global__ __launch_bounds__(256) void k_sort(const int* __restrict__ seq) {
  __shared__ int hist[MAXDEG + 1];
  __shared__ int offs[MAXDEG + 1];
  const int tid = threadIdx.x;
  if (tid <= MAXDEG) hist[tid] = 0;
  __syncthreads();
  if (tid == 0) {
    int any = 0;
    for (int b = 0; b < 64; b++) any |= g_anyArr[b];
    g_mode = any ? 1 : 0;
  }
  for (int i = tid; i < N_NODES; i += 256)
    atomicAdd(&hist[min(max(seq[i], 0), MAXDEG)], 1);
  __syncthreads();
  if (tid == 0) {
    int run = 0;
    for (int L = MAXDEG; L >= 0; L--) { offs[L] = run; run += hist[L]; }
  }
  __syncthreads();
  for (int i = tid; i < N_NODES; i += 256) {
    int p = atomicAdd(&offs[min(max(seq[i], 0), MAXDEG)], 1);
    g_perm[p] = i;
  }
}

// K1: Wh = h @ W (fp64 acc), s1/s2 fp64 dots. Unchanged from r6/r7.
__global__ __launch_bounds__(256) void k_wh(
    const void* __restrict__ h, const void* __restrict__ W, const void* __restrict__ a)
{
  const bool bf16 = (g_mode == 1);
  __shared__ float Ws[F_INN * F_OUTT];   // 64 KB
  const int tid = threadIdx.x;
  if (bf16) {
    const ushort4* Wu = (const ushort4*)W;
    for (int v = tid; v < F_INN * F_OUTT / 4; v += 256) {
      ushort4 u = Wu[v];
      ((float4*)Ws)[v] = make_float4(bf2f(u.x), bf2f(u.y), bf2f(u.z), bf2f(u.w));
    }
  } else {
    const float4* Wf = (const float4*)W;
    for (int v = tid; v < F_INN * F_OUTT / 4; v += 256) ((float4*)Ws)[v] = Wf[v];
  }
  __syncthreads();
  const int wave = tid >> 6, lane = tid & 63;
  const int row = blockIdx.x * 4 + wave;
  float hr0, hr1, hr2, hr3;
  if (bf16) {
    ushort4 v = ((const ushort4*)((const unsigned short*)h + row * F_INN))[lane];
    hr0 = bf2f(v.x); hr1 = bf2f(v.y); hr2 = bf2f(v.z); hr3 = bf2f(v.w);
  } else {
    float4 v = ((const float4*)((const float*)h + row * F_INN))[lane];
    hr0 = v.x; hr1 = v.y; hr2 = v.z; hr3 = v.w;
  }
  double acc = 0.0;
  #pragma unroll 8
  for (int l = 0; l < 64; l++) {
    float h0 = bcastf(hr0, l), h1 = bcastf(hr1, l);
    float h2 = bcastf(hr2, l), h3 = bcastf(hr3, l);
    acc += (double)h0 * (double)Ws[(l * 4 + 0) * F_OUTT + lane];
    acc += (double)h1 * (double)Ws[(l * 4 + 1) * F_OUTT + lane];
    acc += (double)h2 * (double)Ws[(l * 4 + 2) * F_OUTT + lane];
    acc += (double)h3 * (double)Ws[(l * 4 + 3) * F_OUTT + lane];
  }
  const float whv = (float)acc;
  g_Wh[row * F_OUTT + lane] = whv;
  float a1, a2;
  if (bf16) {
    a1 = bf2f(((const unsigned short*)a)[lane]);
    a2 = bf2f(((const unsigned short*)a)[F_OUTT + lane]);
  } else {
    a1 = ((const float*)a)[lane];
    a2 = ((const float*)a)[F_OUTT + lane];
  }
  double t1 = (double)whv * (double)a1;
  double t2 = (double)whv * (double)a2;
  #pragma unroll
  for (int off = 32; off > 0; off >>= 1) {
    t1 += __shfl_down(t1, off);
    t2 += __shfl_down(t2, off);
  }
  if (lane == 0) { g_s1[row] = (float)t1; g_s2[row] = (float)t2; }
}

// K2: attention + fused GX (GX now computed in BOTH modes; the MFMA LSTM
// consumes it for the x-side, keeping fp64-grade x contributions).
__global__ __launch_bounds__(256) void k_att(
    const void* __restrict__ adj, const void* __restrict__ w_ih)
{
  const bool bf16 = (g_mode == 1);
  const int i = blockIdx.x, tid = threadIdx.x;
  __shared__ int    nbr[MAXDEG];
  __shared__ float  att_s[MAXDEG];
  __shared__ int    sorted_j[MAXDEG];
  __shared__ double part[4][F_OUTT];
  __shared__ float  wh2row[F_OUTT];
  __shared__ int    cnt;
  if (tid == 0) cnt = 0;
  __syncthreads();
  if (bf16) {
    const uint4* ar = (const uint4*)((const unsigned short*)adj + (size_t)i * N_NODES);
    for (int c = tid; c < N_NODES / 8; c += 256) {
      uint4 v = ar[c];
      unsigned int w[4] = {v.x, v.y, v.z, v.w};
      #pragma unroll
      for (int k = 0; k < 4; k++) {
        if (w[k] & 0x0000FFFFu) { int p = atomicAdd(&cnt, 1); if (p < MAXDEG) nbr[p] = c*8 + k*2; }
        if (w[k] & 0xFFFF0000u) { int p = atomicAdd(&cnt, 1); if (p < MAXDEG) nbr[p] = c*8 + k*2 + 1; }
      }
    }
  } else {
    const float4* ar = (const float4*)((const float*)adj + (size_t)i * N_NODES);
    for (int c = tid; c < N_NODES / 4; c += 256) {
      float4 v = ar[c];
      if (v.x != 0.0f) { int p = atomicAdd(&cnt, 1); if (p < MAXDEG) nbr[p] = c*4;     }
      if (v.y != 0.0f) { int p = atomicAdd(&cnt, 1); if (p < MAXDEG) nbr[p] = c*4 + 1; }
      if (v.z != 0.0f) { int p = atomicAdd(&cnt, 1); if (p < MAXDEG) nbr[p] = c*4 + 2; }
      if (v.w != 0.0f) { int p = atomicAdd(&cnt, 1); if (p < MAXDEG) nbr[p] = c*4 + 3; }
    }
  }
  __syncthreads();
  const int L = min(cnt, MAXDEG);
  float ef = -3.0e38f; int jn = 0x7fffffff;
  if (tid < L) {
    jn = nbr[tid];
    float s = g_s1[i] + g_s2[jn];
    ef = (s > 0.0f) ? s : 0.2f * s;
  }
  float af = 0.0f;
  if (tid < 64) {
    float m = ef;
    #pragma unroll
    for (int off = 32; off > 0; off >>= 1) m = fmaxf(m, __shfl_down(m, off));
    m = __shfl(m, 0);
    double p = (tid < L) ? exp((double)(ef - m)) : 0.0;
    double ssum = p;
    #pragma unroll
    for (int off = 32; off > 0; off >>= 1) ssum += __shfl_down(ssum, off);
    ssum = __shfl(ssum, 0);
    af = (float)(p / ssum);
    att_s[tid] = af;
  }
  __syncthreads();
  if (tid < L) {
    int rank = 0;
    for (int q = 0; q < L; q++) {
      float aq = att_s[q]; int jq = nbr[q];
      if (aq > af || (aq == af && jq < jn)) rank++;
    }
    sorted_j[rank] = jn;
  }
  {
    const int wave = tid >> 6, lane = tid & 63;
    double acc = 0.0;
    for (int q = wave; q < L; q += 4)
      acc += (double)att_s[q] * (double)g_Wh[(size_t)nbr[q] * F_OUTT + lane];
    part[wave][lane] = acc;
  }
  __syncthreads();
  if (tid < MAXDEG)
    g_rev[i * MAXDEG + tid] = (tid < L) ? sorted_j[L - 1 - tid] : 0;
  if (tid < 64)
    wh2row[tid] = (float)(part[0][tid] + part[1][tid] + part[2][tid] + part[3][tid]);
  __syncthreads();
  // Fused GX (both modes): gate-row tid: dot(w_ih[tid,:], wh2row), fp64.
  {
    double acc = 0.0;
    if (bf16) {
      const uint2* wrow = (const uint2*)((const unsigned short*)w_ih + (size_t)tid * F_OUTT);
      #pragma unroll
      for (int q = 0; q < 16; q++) {
        uint2 v = wrow[q];
        acc += (double)bf2f((unsigned short)(v.x & 0xFFFFu)) * (double)wh2row[q*4 + 0];
        acc += (double)bf2f((unsigned short)(v.x >> 16))     * (double)wh2row[q*4 + 1];
        acc += (double)bf2f((unsigned short)(v.y & 0xFFFFu)) * (double)wh2row[q*4 + 2];
        acc += (double)bf2f((unsigned short)(v.y >> 16))     * (double)wh2row[q*4 + 3];
      }
    } else {
      const float4* wrow = (const float4*)((const float*)w_ih + (size_t)tid * F_OUTT);
      #pragma unroll
      for (int q = 0; q < 16; q++) {
        float4 v = wrow[q];
        acc += (double)v.x * (double)wh2row[q*4 + 0];
        acc += (double)v.y * (double)wh2row[q*4 + 1];
        acc += (double)v.z * (double)wh2row[q*4 + 2];
        acc += (double)v.w * (double)wh2row[q*4 + 3];
      }
    }
    ((float*)g_GX)[(i * F_OUTT + (tid & 63)) * 4 + (tid >> 6)] = (float)acc;
  }
}

// K4-MFMA (both modes): 16 sorted rows/block, grid 256, 4 waves.
// gates(16x256) = h(16x64) @ w_hh^T via v_mfma_f32_16x16x32_bf16 with
// fp32 emulated by bf16 hi/lo splits of BOTH h and w_hh (products kept:
// hh*Whi, hl*Whi, hh*Wlo; dropped hl*Wlo ~2^-18 rel). x-side comes from the
// precomputed fp64-grade g_GX via one float4 gather per (row, step),
// prefetched one step ahead (indices two ahead).
// Wave w owns gate-tiles n = {w, w+4, w+8, w+12} -> full (i,f,g,o) quads for
// units 16w..16w+15 -> no cross-wave exchange; h round-trips through an
// 8.7 KB double-buffered LDS transpose (1 barrier/step).
// Layouts (m89/m91/m93-verified): A[m=lane&15][k=(lane>>4)*8+j];
// B[k=(lane>>4)*8+j][n=lane&15] (B^T-style contiguous row load);
// C col=lane&15, row=(lane>>4)*4+reg.
__global__ __launch_bounds__(256, 1) void k_lstm_mfma(
    const void* __restrict__ w_hh, const void* __restrict__ b_ih,
    const void* __restrict__ b_hh, const int* __restrict__ seq,
    void* __restrict__ out)
{
  const bool bf16 = (g_mode == 1);
  __shared__ __align__(16) float lds_h[2][16 * 68];
  const int tid = threadIdx.x;
  const int w = tid >> 6, lane = tid & 63;
  const int q = lane >> 4, c = lane & 15;
  const int rb = blockIdx.x * 16;

  const int Lmax = min(max(seq[g_perm[rb] & (N_NODES - 1)], 0), MAXDEG);
  int row_e[4], Ls_e[4], rvb[4];
  #pragma unroll
  for (int r = 0; r < 4; r++) {
    row_e[r] = g_perm[rb + q * 4 + r] & (N_NODES - 1);
    Ls_e[r]  = min(max(seq[row_e[r]], 0), MAXDEG);
    rvb[r]   = row_e[r] * MAXDEG;
  }
  const int d_unit = 16 * w + c;   // unit index 0..63 handled by this lane

  // B fragments (loaded once): col = unit 64g + 16w + c, k-chunk ch.
  bf16x8 Bhi[4][2], Blo[4][2];
  float bs[4];
  #pragma unroll
  for (int g = 0; g < 4; g++) {
    const int col = 64 * g + d_unit;
    #pragma unroll
    for (int ch = 0; ch < 2; ch++) {
      if (bf16) {
        Bhi[g][ch] = *(const bf16x8*)((const unsigned short*)w_hh + (size_t)col * 64 + ch * 32 + q * 8);
        Blo[g][ch] = zfrag();
      } else {
        const float* wp = (const float*)w_hh + (size_t)col * 64 + ch * 32 + q * 8;
        hilo(*(const float4*)wp, *(const float4*)(wp + 4), Bhi[g][ch], Blo[g][ch]);
      }
    }
    bs[g] = bf16
      ? bf2f(((const unsigned short*)b_ih)[col]) + bf2f(((const unsigned short*)b_hh)[col])
      : ((const float*)b_ih)[col] + ((const float*)b_hh)[col];
  }

  // gx pipeline: gxq = step t's quads; src_n = node for step t+1.
  float4 gxq[4];
  int src_n[4];
  #pragma unroll
  for (int r = 0; r < 4; r++) {
    int s0 = g_rev[rvb[r]] & (N_NODES - 1);
    gxq[r]  = g_GX[s0 * F_OUTT + d_unit];
    src_n[r] = g_rev[rvb[r] + 1] & (N_NODES - 1);
  }

  bf16x8 hh0 = zfrag(), hh1 = zfrag(), hl0 = zfrag(), hl1 = zfrag();
  float cst[4] = {0.f, 0.f, 0.f, 0.f}, hst[4] = {0.f, 0.f, 0.f, 0.f};

  for (int t = 0; t < Lmax; t++) {
    // prefetch: indices for t+2, gx quads for t+1 (src_n already resident)
    int src_n2[4];
    float4 ngx[4];
    #pragma unroll
    for (int r = 0; r < 4; r++) {
      src_n2[r] = g_rev[rvb[r] + min(t + 2, MAXDEG - 1)] & (N_NODES - 1);
      ngx[r]    = g_GX[src_n[r] * F_OUTT + d_unit];
    }
    float gxa[4][4];
    #pragma unroll
    for (int r = 0; r < 4; r++) {
      gxa[0][r] = gxq[r].x; gxa[1][r] = gxq[r].y;
      gxa[2][r] = gxq[r].z; gxa[3][r] = gxq[r].w;
    }
    f32x4 acc[4];
    #pragma unroll
    for (int g = 0; g < 4; g++) {
      f32x4 a;
      a[0] = bs[g] + gxa[g][0]; a[1] = bs[g] + gxa[g][1];
      a[2] = bs[g] + gxa[g][2]; a[3] = bs[g] + gxa[g][3];
      a = MFMA16(hh0, Bhi[g][0], a);
      a = MFMA16(hh1, Bhi[g][1], a);
      a = MFMA16(hl0, Bhi[g][0], a);
      a = MFMA16(hl1, Bhi[g][1], a);
      a = MFMA16(hh0, Blo[g][0], a);
      a = MFMA16(hh1, Blo[g][1], a);
      acc[g] = a;
    }
    float* lh = lds_h[t & 1];
    #pragma unroll
    for (int r = 0; r < 4; r++) {
      float ig = sigm(acc[0][r]);
      float fg = sigm(acc[1][r]);
      float gg = tanh_fast(acc[2][r]);
      float og = sigm(acc[3][r]);
      float cn = fg * cst[r] + ig * gg;
      float hn = og * tanh_fast(cn);
      bool live = (t < Ls_e[r]);
      cst[r] = live ? cn : cst[r];
      hst[r] = live ? hn : hst[r];
      lh[(q * 4 + r) * 68 + d_unit] = hst[r];
    }
    __syncthreads();
    // rebuild h A-fragments: lane (q,c) -> A[m=c][k=ch*32+8q+j]
    float4 v0 = *(const float4*)&lh[c * 68 + 8 * q];
    float4 v1 = *(const float4*)&lh[c * 68 + 8 * q + 4];
    float4 v2 = *(const float4*)&lh[c * 68 + 32 + 8 * q];
    float4 v3 = *(const float4*)&lh[c * 68 + 32 + 8 * q + 4];
    hilo(v0, v1, hh0, hl0);
    hilo(v2, v3, hh1, hl1);
    #pragma unroll
    for (int r = 0; r < 4; r++) { gxq[r] = ngx[r]; src_n[r] = src_n2[r]; }
  }
  #pragma unroll
  for (int r = 0; r < 4; r++) {
    if (bf16) ((__hip_bfloat16*)out)[row_e[r] * HID + d_unit] = __float2bfloat16(hst[r]);
    else      ((float*)out)[row_e[r] * HID + d_unit] = hst[r];
  }
}

extern "C" void kernel_launch(void* const* d_in, const int* in_sizes, int n_in,
                              void* d_out, int out_size, void* d_ws, size_t ws_size,
                              hipStream_t stream) {
  (void)in_sizes; (void)n_in; (void)out_size; (void)d_ws; (void)ws_size;
  const void* h    = d_in[0];
  const void* adj  = d_in[1];
  const int*  seq  = (const int*)d_in[2];
  const void* W    = d_in[3];
  const void* a    = d_in[4];
  const void* w_ih = d_in[5];
  const void* w_hh = d_in[6];
  const void* b_ih = d_in[7];
  const void* b_hh = d_in[8];

  k_detect   <<<64,           256, 0, stream>>>((const unsigned int*)adj);
  k_sort     <<<1,            256, 0, stream>>>(seq);
  k_wh       <<<N_NODES / 4,  256, 0, stream>>>(h, W, a);
  k_att      <<<N_NODES,      256, 0, stream>>>(adj, w_ih);
  k_lstm_mfma<<<N_NODES / 16, 256, 0, stream>>>(w_hh, b_ih, b_hh, seq, d_out);
}